// Round 3
// baseline (330.228 us; speedup 1.0000x reference)
//
#include <hip/hip_runtime.h>
#include <hip/hip_bf16.h>

// Problem constants
#define NB    2048   // batch
#define SS    200    // seq len
#define STP   208    // padded to 13*16
#define NTIL  13     // s-tiles of 16
#define DSEQ  256
#define DITEM 64
#define AA    128    // attn dim (H=1, HD=128)

typedef __bf16 bf16x8 __attribute__((ext_vector_type(8)));
typedef float  f32x4  __attribute__((ext_vector_type(4)));

__device__ __forceinline__ float prelu_f(float x, float a) { return x >= 0.f ? x : a * x; }

// DPP row (16-lane) rotate helpers — VALU pipe, no LDS traffic.
#define ROR_F(x, n) __int_as_float(__builtin_amdgcn_update_dpp(0, __float_as_int(x), 0x120 + (n), 0xf, 0xf, true))
__device__ __forceinline__ float row_sum16(float x) {
    x += ROR_F(x, 1); x += ROR_F(x, 2); x += ROR_F(x, 4); x += ROR_F(x, 8);
    return x;
}
__device__ __forceinline__ float row_max16(float x) {
    x = fmaxf(x, ROR_F(x, 1)); x = fmaxf(x, ROR_F(x, 2));
    x = fmaxf(x, ROR_F(x, 4)); x = fmaxf(x, ROR_F(x, 8));
    return x;
}

// ---------------- prep: convert W_k|W_v to bf16 [256][256]
__global__ void prep_kernel(const float* __restrict__ Wk, const float* __restrict__ Wv,
                            __hip_bfloat16* __restrict__ Wb) {
    int idx = blockIdx.x * 256 + threadIdx.x;   // 256 blocks -> 65536
    int a = idx >> 8, d = idx & 255;
    float v = (a < 128) ? Wk[a * 256 + d] : Wv[(a - 128) * 256 + d];
    Wb[idx] = __float2bfloat16(v);
}

// ---------------- main fused kernel: one block (8 waves) per batch row
__global__ __launch_bounds__(512, 4) void pool_main(
    const float* __restrict__ X,      // [2048,200,256]
    const int*   __restrict__ maskp,  // [2048,200] 1 = pad
    const float* __restrict__ temb,   // [2048,64]
    const float* __restrict__ Wq,     // [128,64]
    const float* __restrict__ Wker,   // [128,128]
    const float* __restrict__ ffnW,   // [256,128] (torch layout [out,in])
    const float* __restrict__ ffnb,   // [256]
    const float* __restrict__ prelu_a,
    const __hip_bfloat16* __restrict__ Wb,   // ws [256][256] bf16 (rows 0..127=K, 128..255=V)
    float* __restrict__ out)          // [2048*256] ffn, then [2048*200] attn
{
    __shared__ __hip_bfloat16 Xs[2][16][256];  // 16 KB, double-buffered bf16 X tiles (swizzled)
    __shared__ float t_lds[DITEM];
    __shared__ float Q_lds[AA];
    __shared__ float u_lds[AA];
    __shared__ int   mask_lds[STP];
    __shared__ float sp[2][8][16];             // [buf][wave][s] score partials
    __shared__ float score_buf[STP];
    __shared__ float out_vec[AA];

    const int b    = blockIdx.x;
    const int tid  = threadIdx.x;
    const int w    = tid >> 6;        // wave 0..7
    const int lane = tid & 63;
    const int col  = lane & 15;
    const int rg   = lane >> 4;       // 0..3
    float pa = *prelu_a;
    const float inv_scale = 0.08838834764831845f;  // 1/sqrt(128)

    // ---- stage small per-b inputs
    if (tid < DITEM) t_lds[tid] = temb[b * DITEM + tid];
    if (tid < STP)   mask_lds[tid] = (tid < SS) ? maskp[b * SS + tid] : 1;
    __syncthreads();

    // ---- Q = prelu(W_q @ t)
    if (tid < AA) {
        const f32x4* wr = reinterpret_cast<const f32x4*>(Wq + tid * DITEM);
        float acc = 0.f;
        #pragma unroll
        for (int d4 = 0; d4 < DITEM / 4; d4++) {
            f32x4 v = wr[d4];
            acc += v[0] * t_lds[d4 * 4 + 0] + v[1] * t_lds[d4 * 4 + 1]
                 + v[2] * t_lds[d4 * 4 + 2] + v[3] * t_lds[d4 * 4 + 3];
        }
        Q_lds[tid] = prelu_f(acc, pa);
    }
    __syncthreads();

    // ---- u = W_kernel @ Q
    if (tid < AA) {
        const f32x4* wr = reinterpret_cast<const f32x4*>(Wker + tid * AA);
        float acc = 0.f;
        #pragma unroll
        for (int c4 = 0; c4 < AA / 4; c4++) {
            f32x4 v = wr[c4];
            acc += v[0] * Q_lds[c4 * 4 + 0] + v[1] * Q_lds[c4 * 4 + 1]
                 + v[2] * Q_lds[c4 * 4 + 2] + v[3] * Q_lds[c4 * 4 + 3];
        }
        u_lds[tid] = acc;
    }
    __syncthreads();

    // ---- weight fragments: wave w owns K-cols [16w,16w+16) and V-cols [16w,16w+16)
    const int cK = 16 * w + col;
    bf16x8 wk[8], wv[8];
    #pragma unroll
    for (int k = 0; k < 8; k++) {
        wk[k] = *reinterpret_cast<const bf16x8*>(Wb + (size_t)cK * 256 + k * 32 + rg * 8);
        wv[k] = *reinterpret_cast<const bf16x8*>(Wb + (size_t)(cK + 128) * 256 + k * 32 + rg * 8);
    }
    float uw = u_lds[cK];
    #pragma unroll
    for (int k = 0; k < 8; k++) asm volatile("" : "+v"(wk[k]), "+v"(wv[k]));
    asm volatile("" : "+v"(pa), "+v"(uw));

    // ---- staging geometry: each wave stages 2 rows of the 16x256 f32 tile
    const int srow  = 2 * w + (lane >> 5);      // row in tile 0..15
    const int chunk = lane & 31;                // 16B chunk within row
    char* wr_base = (char*)&Xs[0][0][0];
    const int wr_off = srow * 512 + ((chunk * 16) ^ ((srow & 7) << 4));

    f32x4 lo0, hi0, lo1, hi1;
    auto issue = [&](int t, f32x4& lo, f32x4& hi) {
        int gr = t * 16 + srow; if (gr > SS - 1) gr = SS - 1;
        const float* p = X + ((size_t)b * SS + gr) * DSEQ + chunk * 8;
        lo = *reinterpret_cast<const f32x4*>(p);
        hi = *reinterpret_cast<const f32x4*>(p + 4);
        asm volatile("" : "+v"(lo), "+v"(hi));   // pin issue point
    };
    auto writeT = [&](int t, f32x4 lo, f32x4 hi) {
        bf16x8 v;
        v[0] = (__bf16)lo[0]; v[1] = (__bf16)lo[1]; v[2] = (__bf16)lo[2]; v[3] = (__bf16)lo[3];
        v[4] = (__bf16)hi[0]; v[5] = (__bf16)hi[1]; v[6] = (__bf16)hi[2]; v[7] = (__bf16)hi[3];
        *reinterpret_cast<bf16x8*>(wr_base + (t & 1) * 8192 + wr_off) = v;
    };

    // ---- prologue: tiles 0,1 in flight; tile 0 into LDS
    issue(0, lo0, hi0);
    issue(1, lo1, hi1);
    writeT(0, lo0, hi0);
    asm volatile("s_waitcnt lgkmcnt(0)" ::: "memory");
    __builtin_amdgcn_s_barrier();
    __builtin_amdgcn_sched_barrier(0);

    float m = -INFINITY, l = 0.f, out_l = 0.f;
    f32x4 aVp = {0.f, 0.f, 0.f, 0.f};
    const char* rd_col = (const char*)&Xs[0][0][0] + col * 512;
    const int rswz = (col & 7) << 4;

    for (int t = 0; t < NTIL; t++) {
        // prefetch tile t+2 into reg slot (t&1); write tile t+1 to LDS buf (t+1)&1
        if (t + 2 < NTIL) { if ((t & 1) == 0) issue(t + 2, lo0, hi0); else issue(t + 2, lo1, hi1); }
        if (t + 1 < NTIL) { if (((t + 1) & 1) == 0) writeT(t + 1, lo0, hi0); else writeT(t + 1, lo1, hi1); }

        // ---- deferred softmax of tile t-1
        if (t > 0) {
            const int q = (t - 1) & 1, s0p = (t - 1) * 16;
            float sc = 0.f;
            #pragma unroll
            for (int ww = 0; ww < 8; ww++) sc += sp[q][ww][col];
            sc *= inv_scale;
            sc = mask_lds[s0p + col] ? -1e9f : sc;
            if (tid < 16) score_buf[s0p + tid] = sc;
            const float tmax = row_max16(sc);
            const float nm = fmaxf(m, tmax);
            const float f  = __expf(m - nm);
            const float e  = __expf(sc - nm);
            const float sum = row_sum16(e);
            l = l * f + sum; m = nm;
            float acc = out_l * f;
            #pragma unroll
            for (int i = 0; i < 4; i++) {
                float wx = __shfl(e, (lane & 48) | (rg * 4 + i), 64);
                acc += wx * prelu_f(aVp[i], pa);
            }
            out_l = acc;
        }

        // ---- MFMA for tile t from LDS bf16 (swizzled reads)
        const char* rb = rd_col + (t & 1) * 8192;
        f32x4 aK = {0.f,0.f,0.f,0.f}, aV = {0.f,0.f,0.f,0.f};
        #pragma unroll
        for (int k = 0; k < 8; k++) {
            bf16x8 af = *reinterpret_cast<const bf16x8*>(rb + ((k * 64 + rg * 16) ^ rswz));
            aK = __builtin_amdgcn_mfma_f32_16x16x32_bf16(af, wk[k], aK, 0, 0, 0);
            aV = __builtin_amdgcn_mfma_f32_16x16x32_bf16(af, wv[k], aV, 0, 0, 0);
        }

        // ---- score partials: reduce over this wave's 16 K-cols (lane&15) via DPP
        f32x4 pr;
        #pragma unroll
        for (int i = 0; i < 4; i++) pr[i] = row_sum16(prelu_f(aK[i], pa) * uw);
        if (col == 0) *reinterpret_cast<f32x4*>(&sp[t & 1][w][rg * 4]) = pr;
        aVp = aV;

        asm volatile("s_waitcnt lgkmcnt(0)" ::: "memory");
        __builtin_amdgcn_s_barrier();
        __builtin_amdgcn_sched_barrier(0);
    }

    // ---- epilogue: softmax of last tile (sp visible after final barrier)
    {
        const int q = (NTIL - 1) & 1, s0p = (NTIL - 1) * 16;
        float sc = 0.f;
        #pragma unroll
        for (int ww = 0; ww < 8; ww++) sc += sp[q][ww][col];
        sc *= inv_scale;
        sc = mask_lds[s0p + col] ? -1e9f : sc;
        if (tid < 16) score_buf[s0p + tid] = sc;
        const float tmax = row_max16(sc);
        const float nm = fmaxf(m, tmax);
        const float f  = __expf(m - nm);
        const float e  = __expf(sc - nm);
        const float sum = row_sum16(e);
        l = l * f + sum; m = nm;
        float acc = out_l * f;
        #pragma unroll
        for (int i = 0; i < 4; i++) {
            float wx = __shfl(e, (lane & 48) | (rg * 4 + i), 64);
            acc += wx * prelu_f(aVp[i], pa);
        }
        out_l = acc;
    }

    // ---- reduce V accumulation across rg groups, normalize
    out_l += __shfl_xor(out_l, 16, 64);
    out_l += __shfl_xor(out_l, 32, 64);
    const float invl = 1.0f / l;
    if (lane < 16) out_vec[16 * w + lane] = out_l * invl;
    __syncthreads();

    // ---- attn output
    if (tid < SS) {
        out[(size_t)NB * DSEQ + (size_t)b * SS + tid] = __expf(score_buf[tid] - m) * invl;
    }

    // ---- FFN: ffn_out[o] = prelu(sum_a out_vec[a] * ffn_W[o,a] + b[o])
    if (tid < DSEQ) {
        const f32x4* wr = reinterpret_cast<const f32x4*>(ffnW + tid * AA);
        float acc = ffnb[tid];
        #pragma unroll 8
        for (int a4 = 0; a4 < AA / 4; a4++) {
            f32x4 v = wr[a4];
            acc += v[0] * out_vec[a4 * 4 + 0] + v[1] * out_vec[a4 * 4 + 1]
                 + v[2] * out_vec[a4 * 4 + 2] + v[3] * out_vec[a4 * 4 + 3];
        }
        out[(size_t)b * DSEQ + tid] = prelu_f(acc, pa);
    }
}

extern "C" void kernel_launch(void* const* d_in, const int* in_sizes, int n_in,
                              void* d_out, int out_size, void* d_ws, size_t ws_size,
                              hipStream_t stream) {
    const float* X    = (const float*)d_in[0];
    const int*   mask = (const int*)  d_in[1];
    const float* temb = (const float*)d_in[2];
    const float* Wq   = (const float*)d_in[3];
    const float* Wk   = (const float*)d_in[4];
    const float* Wv   = (const float*)d_in[5];
    const float* Wker = (const float*)d_in[6];
    const float* ffnW = (const float*)d_in[7];
    const float* ffnb = (const float*)d_in[8];
    const float* pa   = (const float*)d_in[9];
    float* out = (float*)d_out;

    __hip_bfloat16* Wb = (__hip_bfloat16*)d_ws;

    prep_kernel<<<256, 256, 0, stream>>>(Wk, Wv, Wb);
    pool_main<<<NB, 512, 0, stream>>>(X, mask, temb, Wq, Wker, ffnW, ffnb, pa, Wb, out);
}